// Round 17
// baseline (125.204 us; speedup 1.0000x reference)
//
#include <hip/hip_runtime.h>

#define B_    32
#define CIN   256
#define COUT  256
#define Hh    56
#define Ww    56
#define HP    58
#define WP    58
#define Kk    2304   // 9 taps * 256 ci
#define NT    36     // K-tiles of BK=64

#define QSCALE 2016.0f
#define QINV   (1.0f/2016.0f)

#define XPAD_BYTES ((size_t)B_*HP*WP*CIN)     // 27,557,888 i8
#define XPAD_GUARD 4096                        // wp-overrun guard (reads only)
#define AWT_OFF    (XPAD_BYTES + XPAD_GUARD)
#define AWT_BYTES  ((size_t)NT*16384)          // weights tiled [kt][kc][slot][16]
#define META_OFF   (AWT_OFF + AWT_BYTES)
#define WS_REQUIRED (META_OFF + 1040)

typedef __attribute__((ext_vector_type(4))) int i32x4;

__device__ __forceinline__ void gload_lds16(const void* g, void* l) {
  __builtin_amdgcn_global_load_lds(
      (const __attribute__((address_space(1))) unsigned int*)g,
      (__attribute__((address_space(3))) unsigned int*)l, 16, 0, 0);
}

// ---- prepass 1: gated weights -> i8, compacted-slot tiled [kt][kc][slot][16]
// Each block recomputes the mask scan locally (perm); block 0 writes meta
// (meta[0]=act, meta[1..256]=perm) for the gemm epilogue.
__global__ __launch_bounds__(256) void prep_w8(const float* __restrict__ wgt,
                                               const float* __restrict__ mask,
                                               int* __restrict__ meta,
                                               signed char* __restrict__ awt) {
  __shared__ int sc[256];
  __shared__ int sperm[256];
  const int t = threadIdx.x;
  const int fl = (mask[t] >= 0.0f) ? 1 : 0;   // scale!=0 iff mask>=0
  sc[t] = fl;
  __syncthreads();
  for (int off = 1; off < 256; off <<= 1) {
    int v = sc[t];
    int u = (t >= off) ? sc[t - off] : 0;
    __syncthreads();
    sc[t] = v + u;
    __syncthreads();
  }
  const int incl = sc[t], act = sc[255];
  const int pos = fl ? (incl - 1) : (act + t - incl);
  sperm[pos] = t;
  __syncthreads();
  if (blockIdx.x == 0) {
    meta[1 + pos] = t;
    if (t == 0) meta[0] = act;
  }
  const int slot = blockIdx.x;
  const int co = sperm[slot];
  const float m = mask[co];
  const float scl = (m > 0.f ? 1.f : (m < 0.f ? 0.f : 0.5f)) * QSCALE;
  const float* wc = wgt + (size_t)co * Kk;       // [ci][tap]
  for (int o = t; o < Kk; o += 256) {
    int tap = o >> 8, ci = o & 255;
    int q = __float2int_rn(wc[ci * 9 + tap] * scl);
    int kt = tap * 4 + (ci >> 6);
    int kk = ci & 63;
    awt[((size_t)kt * 1024 + (kk >> 4) * 256 + slot) * 16 + (kk & 15)] =
        (signed char)q;
  }
}

// ---- prepass 2: sign(x) -> i8 {-1,0,1}, zero-pad, NCHW -> [b][hp][wp][ci]
__global__ __launch_bounds__(256) void prep_x8(const float* __restrict__ x,
                                               signed char* __restrict__ xp) {
  const int hp = blockIdx.x, b = blockIdx.y, t = threadIdx.x;
  unsigned* orow = (unsigned*)(xp + (size_t)(b * HP + hp) * WP * CIN);
  if (hp == 0 || hp == HP - 1) {
    for (int i = t; i < WP * CIN / 4; i += 256) orow[i] = 0u;
    return;
  }
  __shared__ __align__(16) signed char tile[WP * CIN];
  const int h = hp - 1;
  tile[t] = 0;
  tile[(WP - 1) * CIN + t] = 0;
  const int tx = t & 63, ty = t >> 6;
  if (tx < Ww) {
    const float* xr = x + ((size_t)b * CIN * Hh + h) * Ww;
    for (int ci = ty; ci < CIN; ci += 4) {
      float xv = xr[(size_t)ci * Hh * Ww + tx];
      tile[(1 + tx) * CIN + ci] = (xv > 0.f) ? 1 : (xv < 0.f ? -1 : 0);
    }
  }
  __syncthreads();
  for (int i = t; i < WP * CIN / 4; i += 256) orow[i] = ((const unsigned*)tile)[i];
}

// ---- main: compacted-M i8 GEMM, occupancy-unlocked. BM=128 (grid_y=2,
// compacted slots), BN=128 (2 padded rows), BK=64. 4 waves (2x2) of 64x64:
// acc[4][4] = 64 AGPR -> ~125 regs/wave -> 4 waves/SIMD. LDS dbuf 2 x
// {A [4kc][128][16] 8KB | B [4kc][128][16] 8KB} = 32KB -> ~3.5 active
// blocks/CU, ~14 waves/CU: TLP finally covers LDS+DMA latency.
// Per KT: STAGE(kt+1 -> buf^1) | 8x ds_read_b128(buf) | 16 MFMA |
// vmcnt(0) | barrier.
// grid=(896 = b*28 + hblk, 2), block=256
__global__ __launch_bounds__(256, 4) void gemm_i8o(
    const signed char* __restrict__ xp,
    const signed char* __restrict__ awt,
    const int* __restrict__ meta,
    float* __restrict__ out) {
  extern __shared__ char smem[];

  const int t = threadIdx.x;
  const int nb = blockIdx.x, by = blockIdx.y;
  const int b = nb / 28, h0 = (nb % 28) * 2;

  const int act = meta[0];
  const int rem = act - by * 128;
  const int ng = (rem <= 0) ? 0 : ((rem > 64) ? 2 : 1);

  const int wid = t >> 6, lane = t & 63;
  const int wm = wid >> 1, wn = wid & 1;     // wave tile: 64 M x 64 N
  const int lc = lane & 15, lr = lane >> 4;

  i32x4 acc[4][4] = {};

  if (ng > 0) {
    // A staging: thread t -> lines {t, 256+t} of [4kc][128 slot][16]
    const signed char* awp =
        awt + (t >> 7) * 4096 + (size_t)(by * 128 + (t & 127)) * 16;
    // B staging: thread t -> lines {t, 256+t} of [4kc][128 n][16]
    const int n = t & 127;
    const size_t xb = (size_t)b * HP;
    const signed char* xbp =
        xp + ((xb + h0 + (n >> 6)) * WP + (n & 63)) * CIN + (t >> 7) * 16;
    char* dstA = smem + t * 16;
    char* dstB = smem + 8192 + t * 16;

    const int abase = lr * 2048 + (wm * 64 + lc) * 16;
    const int bbase = 8192 + lr * 2048 + (wn * 64 + lc) * 16;
    const bool run = (wm < ng);

#define STAGE_Ak(ktx, BUF) do {                                                \
    const signed char* s_ = awp + (size_t)(ktx) * 16384;                       \
    char* d_ = dstA + (BUF) * 16384;                                           \
    gload_lds16(s_, d_);                                                       \
    gload_lds16(s_ + 8192, d_ + 4096);                                         \
  } while (0)

#define STAGE_Bk(ktx, BUF) do {                                                \
    int tap_ = (ktx) >> 2;                                                     \
    int kh_ = tap_ / 3, kw_ = tap_ - kh_ * 3;                                  \
    const signed char* s_ = xbp + (kh_ * WP + kw_) * CIN + ((ktx) & 3) * 64;   \
    char* d_ = dstB + (BUF) * 16384;                                           \
    gload_lds16(s_, d_);                                                       \
    gload_lds16(s_ + 32, d_ + 4096);                                           \
  } while (0)

    // prologue: stage kt0 -> buf0, drain, publish
    STAGE_Ak(0, 0);
    STAGE_Bk(0, 0);
    asm volatile("s_waitcnt vmcnt(0)" ::: "memory");
    __builtin_amdgcn_sched_barrier(0);
    __builtin_amdgcn_s_barrier();
    __builtin_amdgcn_sched_barrier(0);

    i32x4 af[4], bf[4];

#pragma unroll 1
    for (int kt = 0; kt < NT; ++kt) {
      const int buf = kt & 1;
      const int kn = (kt + 1 < NT) ? kt + 1 : NT - 1;  // tail: harmless dummy
      STAGE_Ak(kn, buf ^ 1);
      STAGE_Bk(kn, buf ^ 1);
      if (run) {
        #pragma unroll
        for (int i_ = 0; i_ < 4; ++i_) {
          af[i_] = *(const i32x4*)(smem + buf * 16384 + abase + i_ * 256);
          bf[i_] = *(const i32x4*)(smem + buf * 16384 + bbase + i_ * 256);
        }
        __builtin_amdgcn_s_setprio(1);
        #pragma unroll
        for (int m_ = 0; m_ < 4; ++m_)
          #pragma unroll
          for (int n_ = 0; n_ < 4; ++n_)
            acc[m_][n_] = __builtin_amdgcn_mfma_i32_16x16x64_i8(
                af[m_], bf[n_], acc[m_][n_], 0, 0, 0);
        __builtin_amdgcn_s_setprio(0);
      }
      asm volatile("s_waitcnt vmcnt(0)" ::: "memory");
      __builtin_amdgcn_sched_barrier(0);
      __builtin_amdgcn_s_barrier();
      __builtin_amdgcn_sched_barrier(0);
    }
  }

  // epilogue: C/D map col(n)=lane&15, row(m)=(lane>>4)*4+reg.
  // slot -> co via perm; skipped/padded rows carry exact zeros.
  const int* perm = meta + 1;
  #pragma unroll
  for (int m = 0; m < 4; ++m) {
    const int slotb = by * 128 + wm * 64 + m * 16 + lr * 4;
    const int c0 = perm[slotb], c1 = perm[slotb + 1];
    const int c2 = perm[slotb + 2], c3 = perm[slotb + 3];
    const int cos[4] = {c0, c1, c2, c3};
    #pragma unroll
    for (int nf = 0; nf < 4; ++nf) {
      const int col = wn * 64 + nf * 16 + lc;
      const int h = h0 + (col >> 6);
      const int w = col & 63;
      if (w < Ww) {
        #pragma unroll
        for (int r = 0; r < 4; ++r)
          out[(((size_t)b * COUT + cos[r]) * Hh + h) * Ww + w] =
              (float)acc[m][nf][r] * QINV;
      }
    }
  }
}

// ---- fallback: proven-correct naive direct conv (used only if ws too small)
__global__ __launch_bounds__(256) void binconv_naive(
    const float* __restrict__ x,
    const float* __restrict__ wgt,
    const float* __restrict__ mask,
    float* __restrict__ out) {
  const int w  = threadIdx.x;
  const int h  = blockIdx.x * 4 + threadIdx.y;
  const int co = blockIdx.y;
  const int b  = blockIdx.z;

  const float m = mask[co];
  const float scale = (m > 0.f) ? 1.f : ((m < 0.f) ? 0.f : 0.5f);

  const size_t obase = (((size_t)b * COUT + co) * Hh + h) * Ww + w;
  if (scale == 0.f) {
    if (w < Ww) out[obase] = 0.f;
    return;
  }

  const float* __restrict__ xb = x   + (size_t)b  * CIN * Hh * Ww;
  const float* __restrict__ wc = wgt + (size_t)co * CIN * 9;

  float acc = 0.f;
  for (int ci = 0; ci < CIN; ++ci) {
    const float* __restrict__ xc = xb + (size_t)ci * (Hh * Ww);
    const float* __restrict__ wk = wc + ci * 9;
    float wv[9];
    #pragma unroll
    for (int t2 = 0; t2 < 9; ++t2) wv[t2] = wk[t2];
    #pragma unroll
    for (int kh = 0; kh < 3; ++kh) {
      const int hh = h + kh - 1;
      if (hh < 0 || hh >= Hh) continue;
      const float* __restrict__ xr = xc + hh * Ww;
      #pragma unroll
      for (int kw = 0; kw < 3; ++kw) {
        const int ww = w + kw - 1;
        float xv = (ww >= 0 && ww < Ww) ? xr[ww] : 0.f;
        float s = (xv > 0.f) ? 1.f : ((xv < 0.f) ? -1.f : 0.f);
        acc += s * wv[kh * 3 + kw];
      }
    }
  }
  if (w < Ww) out[obase] = acc * scale;
}

extern "C" void kernel_launch(void* const* d_in, const int* in_sizes, int n_in,
                              void* d_out, int out_size, void* d_ws, size_t ws_size,
                              hipStream_t stream) {
  const float* x    = (const float*)d_in[0];
  const float* wgt  = (const float*)d_in[1];
  const float* mask = (const float*)d_in[2];
  float* out = (float*)d_out;

  bool ok = ws_size >= WS_REQUIRED;
  if (ok) {
    hipError_t e = hipFuncSetAttribute(
        (const void*)gemm_i8o, hipFuncAttributeMaxDynamicSharedMemorySize,
        32768);
    ok = (e == hipSuccess);
  }
  if (!ok) {
    hipLaunchKernelGGL(binconv_naive, dim3(Hh / 4, COUT, B_), dim3(64, 4, 1),
                       0, stream, x, wgt, mask, out);
    return;
  }

  signed char* xp8 = (signed char*)d_ws;
  signed char* awt = (signed char*)d_ws + AWT_OFF;
  int* meta        = (int*)((char*)d_ws + META_OFF);

  hipLaunchKernelGGL(prep_w8, dim3(COUT), dim3(256), 0, stream, wgt, mask,
                     meta, awt);
  hipLaunchKernelGGL(prep_x8, dim3(HP, B_), dim3(256), 0, stream, x, xp8);
  hipLaunchKernelGGL(gemm_i8o, dim3(896, 2), dim3(256), 32768, stream,
                     xp8, awt, meta, out);
}

// Round 18
// 123.578 us; speedup vs baseline: 1.0132x; 1.0132x over previous
//
#include <hip/hip_runtime.h>

#define B_    32
#define CIN   256
#define COUT  256
#define Hh    56
#define Ww    56
#define HP    58
#define WP    58
#define Kk    2304   // 9 taps * 256 ci
#define NT    36     // K-tiles of BK=64

#define QSCALE 2016.0f
#define QINV   (1.0f/2016.0f)

#define XPAD_BYTES ((size_t)B_*HP*WP*CIN)     // 27,557,888 i8
#define XPAD_GUARD 4096                        // wp-overrun guard (reads only)
#define AWT_OFF    (XPAD_BYTES + XPAD_GUARD)
#define AWT_BYTES  ((size_t)NT*16384)          // weights tiled [kt][kc][slot][16]
#define META_OFF   (AWT_OFF + AWT_BYTES)
#define WS_REQUIRED (META_OFF + 1040)

typedef __attribute__((ext_vector_type(4))) int i32x4;

__device__ __forceinline__ void gload_lds16(const void* g, void* l) {
  __builtin_amdgcn_global_load_lds(
      (const __attribute__((address_space(1))) unsigned int*)g,
      (__attribute__((address_space(3))) unsigned int*)l, 16, 0, 0);
}

// ---- prepass 1: gated weights -> i8, compacted-slot tiled [kt][kc][slot][16]
// Each block recomputes the mask scan locally (perm); block 0 writes meta
// (meta[0]=act, meta[1..256]=perm) for the gemm epilogue.
__global__ __launch_bounds__(256) void prep_w8(const float* __restrict__ wgt,
                                               const float* __restrict__ mask,
                                               int* __restrict__ meta,
                                               signed char* __restrict__ awt) {
  __shared__ int sc[256];
  __shared__ int sperm[256];
  const int t = threadIdx.x;
  const int fl = (mask[t] >= 0.0f) ? 1 : 0;   // scale!=0 iff mask>=0
  sc[t] = fl;
  __syncthreads();
  for (int off = 1; off < 256; off <<= 1) {
    int v = sc[t];
    int u = (t >= off) ? sc[t - off] : 0;
    __syncthreads();
    sc[t] = v + u;
    __syncthreads();
  }
  const int incl = sc[t], act = sc[255];
  const int pos = fl ? (incl - 1) : (act + t - incl);
  sperm[pos] = t;
  __syncthreads();
  if (blockIdx.x == 0) {
    meta[1 + pos] = t;
    if (t == 0) meta[0] = act;
  }
  const int slot = blockIdx.x;
  const int co = sperm[slot];
  const float m = mask[co];
  const float scl = (m > 0.f ? 1.f : (m < 0.f ? 0.f : 0.5f)) * QSCALE;
  const float* wc = wgt + (size_t)co * Kk;       // [ci][tap]
  for (int o = t; o < Kk; o += 256) {
    int tap = o >> 8, ci = o & 255;
    int q = __float2int_rn(wc[ci * 9 + tap] * scl);
    int kt = tap * 4 + (ci >> 6);
    int kk = ci & 63;
    awt[((size_t)kt * 1024 + (kk >> 4) * 256 + slot) * 16 + (kk & 15)] =
        (signed char)q;
  }
}

// ---- prepass 2: sign(x) -> i8 {-1,0,1}, zero-pad, NCHW -> [b][hp][wp][ci]
__global__ __launch_bounds__(256) void prep_x8(const float* __restrict__ x,
                                               signed char* __restrict__ xp) {
  const int hp = blockIdx.x, b = blockIdx.y, t = threadIdx.x;
  unsigned* orow = (unsigned*)(xp + (size_t)(b * HP + hp) * WP * CIN);
  if (hp == 0 || hp == HP - 1) {
    for (int i = t; i < WP * CIN / 4; i += 256) orow[i] = 0u;
    return;
  }
  __shared__ __align__(16) signed char tile[WP * CIN];
  const int h = hp - 1;
  tile[t] = 0;
  tile[(WP - 1) * CIN + t] = 0;
  const int tx = t & 63, ty = t >> 6;
  if (tx < Ww) {
    const float* xr = x + ((size_t)b * CIN * Hh + h) * Ww;
    for (int ci = ty; ci < CIN; ci += 4) {
      float xv = xr[(size_t)ci * Hh * Ww + tx];
      tile[(1 + tx) * CIN + ci] = (xv > 0.f) ? 1 : (xv < 0.f ? -1 : 0);
    }
  }
  __syncthreads();
  for (int i = t; i < WP * CIN / 4; i += 256) orow[i] = ((const unsigned*)tile)[i];
}

// ---- main: compacted-M i8 GEMM = r14 structure (BM=128 grid_y=2, BN=256,
// BK=64, tri-buffer 3x24KB, depth-2 counted vmcnt) at r17 register shape:
// 8 waves (2M x 4N) of 64x64, acc[4][4]=64 AGPR -> ~125 regs -> 4 waves/SIMD,
// 2 blocks/CU co-resident = 16 waves/CU to fill latency gaps.
// Per KT: STAGE(kt+2 -> sb) [3 loads/thread] | frag reads(rb) | 16 MFMA |
// vmcnt(3) (drain kt+1, keep kt+2) | barrier | rotate {rb,rbn,sb}.
// grid=(448 = b*14 + hblk, 2), block=512
__global__ __launch_bounds__(512, 4) void gemm_i8t(
    const signed char* __restrict__ xp,
    const signed char* __restrict__ awt,
    const int* __restrict__ meta,
    float* __restrict__ out) {
  extern __shared__ char smem[];

  const int t = threadIdx.x;
  const int nb = blockIdx.x, by = blockIdx.y;
  const int b = nb / 14, h0 = (nb % 14) * 4;

  const int act = meta[0];
  const int rem = act - by * 128;
  const int ng = (rem <= 0) ? 0 : ((rem > 64) ? 2 : 1);

  const int wid = t >> 6, lane = t & 63;
  const int wm = wid >> 2, wn = wid & 3;     // 2M x 4N waves of 64x64
  const int lc = lane & 15, lr = lane >> 4;

  i32x4 acc[4][4] = {};

  if (ng > 0) {
    // A staging: 512 threads x 1 load cover [4kc][128 slot][16] = 8KB
    const signed char* awp =
        awt + (t >> 7) * 4096 + (size_t)(by * 128 + (t & 127)) * 16;
    // B staging: 512 threads x 2 loads cover [4kc][256 n][16] = 16KB
    const int n = t & 255;
    const size_t xb = (size_t)b * HP;
    const signed char* xbp =
        xp + ((xb + h0 + (n >> 6)) * WP + (n & 63)) * CIN + (t >> 8) * 16;
    char* dstA = smem + t * 16;              // A region [0, 8192)
    char* dstB = smem + 8192 + t * 16;       // B region [8192, 24576)

    const int abase = lr * 2048 + (wm * 64 + lc) * 16;
    const int bbase = 8192 + lr * 4096 + (wn * 64 + lc) * 16;
    const bool run = (wm < ng);

#define STAGE_Ak(ktx, BO)                                                      \
    gload_lds16(awp + (size_t)(ktx) * 16384, dstA + (BO))

#define STAGE_Bk(ktx, BO) do {                                                 \
    int tap_ = (ktx) >> 2;                                                     \
    int kh_ = tap_ / 3, kw_ = tap_ - kh_ * 3;                                  \
    const signed char* s_ = xbp + (kh_ * WP + kw_) * CIN + ((ktx) & 3) * 64;   \
    gload_lds16(s_, dstB + (BO));                                              \
    gload_lds16(s_ + 32, dstB + (BO) + 8192);                                  \
  } while (0)

    // prologue: kt0 -> buf0, kt1 -> buf1 (6 loads/thread); drain kt0 (keep 3)
    STAGE_Ak(0, 0); STAGE_Bk(0, 0);
    STAGE_Ak(1, 24576); STAGE_Bk(1, 24576);
    asm volatile("s_waitcnt vmcnt(3)" ::: "memory");
    __builtin_amdgcn_sched_barrier(0);
    __builtin_amdgcn_s_barrier();
    __builtin_amdgcn_sched_barrier(0);

    int rb = 0, rbn = 24576, sb = 49152;
    i32x4 af[4], bf[4];

#pragma unroll 1
    for (int kt = 0; kt < NT; ++kt) {
      const int kn = (kt + 2 < NT) ? kt + 2 : NT - 1;   // tail dummy ok
      STAGE_Ak(kn, sb);
      STAGE_Bk(kn, sb);
      if (run) {
        #pragma unroll
        for (int i_ = 0; i_ < 4; ++i_) {
          af[i_] = *(const i32x4*)(smem + rb + abase + i_ * 256);
          bf[i_] = *(const i32x4*)(smem + rb + bbase + i_ * 256);
        }
        __builtin_amdgcn_s_setprio(1);
        #pragma unroll
        for (int m_ = 0; m_ < 4; ++m_)
          #pragma unroll
          for (int n_ = 0; n_ < 4; ++n_)
            acc[m_][n_] = __builtin_amdgcn_mfma_i32_16x16x64_i8(
                af[m_], bf[n_], acc[m_][n_], 0, 0, 0);
        __builtin_amdgcn_s_setprio(0);
      }
      // drain kt+1's 3 loads (issued last iter), keep this iter's 3 (kt+2)
      asm volatile("s_waitcnt vmcnt(3)" ::: "memory");
      __builtin_amdgcn_sched_barrier(0);
      __builtin_amdgcn_s_barrier();
      __builtin_amdgcn_sched_barrier(0);
      int tmp_ = rb; rb = rbn; rbn = sb; sb = tmp_;
    }
    asm volatile("s_waitcnt vmcnt(0)" ::: "memory");  // drain tail dummies
  }

  // epilogue: C/D map col(n)=lane&15, row(m)=(lane>>4)*4+reg.
  // slot -> co via perm; skipped/padded rows carry exact zeros.
  const int* perm = meta + 1;
  #pragma unroll
  for (int m = 0; m < 4; ++m) {
    const int slotb = by * 128 + wm * 64 + m * 16 + lr * 4;
    const int c0 = perm[slotb], c1 = perm[slotb + 1];
    const int c2 = perm[slotb + 2], c3 = perm[slotb + 3];
    const int cos[4] = {c0, c1, c2, c3};
    #pragma unroll
    for (int nf = 0; nf < 4; ++nf) {
      const int col = wn * 64 + nf * 16 + lc;
      const int h = h0 + (col >> 6);
      const int w = col & 63;
      if (w < Ww) {
        #pragma unroll
        for (int r = 0; r < 4; ++r)
          out[(((size_t)b * COUT + cos[r]) * Hh + h) * Ww + w] =
              (float)acc[m][nf][r] * QINV;
      }
    }
  }
}

// ---- fallback: proven-correct naive direct conv (used only if ws too small)
__global__ __launch_bounds__(256) void binconv_naive(
    const float* __restrict__ x,
    const float* __restrict__ wgt,
    const float* __restrict__ mask,
    float* __restrict__ out) {
  const int w  = threadIdx.x;
  const int h  = blockIdx.x * 4 + threadIdx.y;
  const int co = blockIdx.y;
  const int b  = blockIdx.z;

  const float m = mask[co];
  const float scale = (m > 0.f) ? 1.f : ((m < 0.f) ? 0.f : 0.5f);

  const size_t obase = (((size_t)b * COUT + co) * Hh + h) * Ww + w;
  if (scale == 0.f) {
    if (w < Ww) out[obase] = 0.f;
    return;
  }

  const float* __restrict__ xb = x   + (size_t)b  * CIN * Hh * Ww;
  const float* __restrict__ wc = wgt + (size_t)co * CIN * 9;

  float acc = 0.f;
  for (int ci = 0; ci < CIN; ++ci) {
    const float* __restrict__ xc = xb + (size_t)ci * (Hh * Ww);
    const float* __restrict__ wk = wc + ci * 9;
    float wv[9];
    #pragma unroll
    for (int t2 = 0; t2 < 9; ++t2) wv[t2] = wk[t2];
    #pragma unroll
    for (int kh = 0; kh < 3; ++kh) {
      const int hh = h + kh - 1;
      if (hh < 0 || hh >= Hh) continue;
      const float* __restrict__ xr = xc + hh * Ww;
      #pragma unroll
      for (int kw = 0; kw < 3; ++kw) {
        const int ww = w + kw - 1;
        float xv = (ww >= 0 && ww < Ww) ? xr[ww] : 0.f;
        float s = (xv > 0.f) ? 1.f : ((xv < 0.f) ? -1.f : 0.f);
        acc += s * wv[kh * 3 + kw];
      }
    }
  }
  if (w < Ww) out[obase] = acc * scale;
}

extern "C" void kernel_launch(void* const* d_in, const int* in_sizes, int n_in,
                              void* d_out, int out_size, void* d_ws, size_t ws_size,
                              hipStream_t stream) {
  const float* x    = (const float*)d_in[0];
  const float* wgt  = (const float*)d_in[1];
  const float* mask = (const float*)d_in[2];
  float* out = (float*)d_out;

  bool ok = ws_size >= WS_REQUIRED;
  if (ok) {
    hipError_t e = hipFuncSetAttribute(
        (const void*)gemm_i8t, hipFuncAttributeMaxDynamicSharedMemorySize,
        73728);
    ok = (e == hipSuccess);
  }
  if (!ok) {
    hipLaunchKernelGGL(binconv_naive, dim3(Hh / 4, COUT, B_), dim3(64, 4, 1),
                       0, stream, x, wgt, mask, out);
    return;
  }

  signed char* xp8 = (signed char*)d_ws;
  signed char* awt = (signed char*)d_ws + AWT_OFF;
  int* meta        = (int*)((char*)d_ws + META_OFF);

  hipLaunchKernelGGL(prep_w8, dim3(COUT), dim3(256), 0, stream, wgt, mask,
                     meta, awt);
  hipLaunchKernelGGL(prep_x8, dim3(HP, B_), dim3(256), 0, stream, x, xp8);
  hipLaunchKernelGGL(gemm_i8t, dim3(448, 2), dim3(512), 73728, stream,
                     xp8, awt, meta, out);
}

// Round 19
// 115.325 us; speedup vs baseline: 1.0857x; 1.0716x over previous
//
#include <hip/hip_runtime.h>

#define B_    32
#define CIN   256
#define COUT  256
#define Hh    56
#define Ww    56
#define HP    58
#define WP    58
#define Kk    2304   // 9 taps * 256 ci
#define NT    18     // K-tiles of BK=128 (2 per tap)

#define QSCALE 2016.0f
#define QINV   (1.0f/2016.0f)

#define XPAD_BYTES ((size_t)B_*HP*WP*CIN)     // 27,557,888 i8
#define XPAD_GUARD 4096                        // wp-overrun guard (reads only)
#define AWT_OFF    (XPAD_BYTES + XPAD_GUARD)
#define AWT_BYTES  ((size_t)NT*32768)          // weights tiled [kt][kc8][slot][16]
#define META_OFF   (AWT_OFF + AWT_BYTES)
#define WS_REQUIRED (META_OFF + 1040)

typedef __attribute__((ext_vector_type(4))) int i32x4;

__device__ __forceinline__ void gload_lds16(const void* g, void* l) {
  __builtin_amdgcn_global_load_lds(
      (const __attribute__((address_space(1))) unsigned int*)g,
      (__attribute__((address_space(3))) unsigned int*)l, 16, 0, 0);
}

// ---- fused prepass: blocks [0, HP*B_) do sign+pad+transpose of x;
// blocks [HP*B_, HP*B_+256) do mask-scan + gated-weight quant (slot-tiled).
// meta[0]=act, meta[1..256]=perm (written by the slot==0 block).
__global__ __launch_bounds__(256) void prep_all(
    const float* __restrict__ x,
    const float* __restrict__ wgt,
    const float* __restrict__ mask,
    int* __restrict__ meta,
    signed char* __restrict__ awt,
    signed char* __restrict__ xp) {
  const int t = threadIdx.x;
  const int bid = blockIdx.x;
  if (bid < HP * B_) {
    const int hp = bid % HP, b = bid / HP;
    unsigned* orow = (unsigned*)(xp + (size_t)(b * HP + hp) * WP * CIN);
    if (hp == 0 || hp == HP - 1) {
      for (int i = t; i < WP * CIN / 4; i += 256) orow[i] = 0u;
      return;
    }
    __shared__ __align__(16) signed char tile[WP * CIN];
    const int h = hp - 1;
    tile[t] = 0;
    tile[(WP - 1) * CIN + t] = 0;
    const int tx = t & 63, ty = t >> 6;
    if (tx < Ww) {
      const float* xr = x + ((size_t)b * CIN * Hh + h) * Ww;
      for (int ci = ty; ci < CIN; ci += 4) {
        float xv = xr[(size_t)ci * Hh * Ww + tx];
        tile[(1 + tx) * CIN + ci] = (xv > 0.f) ? 1 : (xv < 0.f ? -1 : 0);
      }
    }
    __syncthreads();
    for (int i = t; i < WP * CIN / 4; i += 256)
      orow[i] = ((const unsigned*)tile)[i];
  } else {
    __shared__ int sc[256];
    __shared__ int sperm[256];
    const int fl = (mask[t] >= 0.0f) ? 1 : 0;   // scale!=0 iff mask>=0
    sc[t] = fl;
    __syncthreads();
    for (int off = 1; off < 256; off <<= 1) {
      int v = sc[t];
      int u = (t >= off) ? sc[t - off] : 0;
      __syncthreads();
      sc[t] = v + u;
      __syncthreads();
    }
    const int incl = sc[t], act = sc[255];
    const int pos = fl ? (incl - 1) : (act + t - incl);
    sperm[pos] = t;
    __syncthreads();
    const int slot = bid - HP * B_;
    if (slot == 0) {
      meta[1 + pos] = t;
      if (t == 0) meta[0] = act;
    }
    const int co = sperm[slot];
    const float m = mask[co];
    const float scl = (m > 0.f ? 1.f : (m < 0.f ? 0.f : 0.5f)) * QSCALE;
    const float* wc = wgt + (size_t)co * Kk;     // [ci][tap]
    for (int o = t; o < Kk; o += 256) {
      int tap = o >> 8, ci = o & 255;
      int q = __float2int_rn(wc[ci * 9 + tap] * scl);
      int kt = tap * 2 + (ci >> 7);              // BK=128 K-tile
      int kk = ci & 127;
      awt[((size_t)kt * 2048 + (kk >> 4) * 256 + slot) * 16 + (kk & 15)] =
          (signed char)q;
    }
  }
}

// ---- main: compacted-M i8 GEMM, BK=128 (NT=18 -> half the barriers).
// BM=128 (grid_y=2, compacted slots), BN=128 (2 padded rows). 4 waves (2x2)
// of 64x64, acc[4][4]=64 AGPR. LDS dbuf 2 x {A [8kc][128][16] 16KB |
// B [8kc][128][16] 16KB} = 64KB -> 2 blocks/CU. Per KT: STAGE(kt+1 -> buf^1,
// 8 loads/thread, hides under ~2000cyc compute) | frags s0 | 16 MFMA |
// frags s1 | 16 MFMA | vmcnt(0) | barrier.
// grid=(896 = b*28 + hblk, 2), block=256
__global__ __launch_bounds__(256, 2) void gemm_i8k(
    const signed char* __restrict__ xp,
    const signed char* __restrict__ awt,
    const int* __restrict__ meta,
    float* __restrict__ out) {
  extern __shared__ char smem[];

  const int t = threadIdx.x;
  const int nb = blockIdx.x, by = blockIdx.y;
  const int b = nb / 28, h0 = (nb % 28) * 2;

  const int act = meta[0];
  const int rem = act - by * 128;
  const int ng = (rem <= 0) ? 0 : ((rem > 64) ? 2 : 1);

  const int wid = t >> 6, lane = t & 63;
  const int wm = wid >> 1, wn = wid & 1;     // wave tile: 64 M x 64 N
  const int lc = lane & 15, lr = lane >> 4;

  i32x4 acc[4][4] = {};

  if (ng > 0) {
    // A staging: 4 loads/thread cover [8kc][128 slot][16] = 16KB
    const signed char* awp =
        awt + (t >> 7) * 4096 + (size_t)(by * 128 + (t & 127)) * 16;
    // B staging: 4 loads/thread cover [8kc][128 n][16] = 16KB
    const int n = t & 127;
    const size_t xb = (size_t)b * HP;
    const signed char* xbp =
        xp + ((xb + h0 + (n >> 6)) * WP + (n & 63)) * CIN + (t >> 7) * 16;
    char* dstA = smem + t * 16;              // A region [0, 16384)
    char* dstB = smem + 16384 + t * 16;      // B region [16384, 32768)

    const int afix = wm * 1024 + lc * 16;    // + s*8192 + lr*2048 + i*256
    const int bfix = 16384 + wn * 1024 + lc * 16;
    const bool run = (wm < ng);

#define STAGE_A128(ktx, BUF) do {                                              \
    const signed char* s_ = awp + (size_t)(ktx) * 32768;                       \
    char* d_ = dstA + (BUF) * 32768;                                           \
    gload_lds16(s_,          d_);                                              \
    gload_lds16(s_ + 8192,   d_ + 4096);                                       \
    gload_lds16(s_ + 16384,  d_ + 8192);                                       \
    gload_lds16(s_ + 24576,  d_ + 12288);                                      \
  } while (0)

#define STAGE_B128(ktx, BUF) do {                                              \
    int tap_ = (ktx) >> 1;                                                     \
    int kh_ = tap_ / 3, kw_ = tap_ - kh_ * 3;                                  \
    const signed char* s_ = xbp + (kh_ * WP + kw_) * CIN + ((ktx) & 1) * 128;  \
    char* d_ = dstB + (BUF) * 32768;                                           \
    gload_lds16(s_,       d_);                                                 \
    gload_lds16(s_ + 32,  d_ + 4096);                                          \
    gload_lds16(s_ + 64,  d_ + 8192);                                          \
    gload_lds16(s_ + 96,  d_ + 12288);                                         \
  } while (0)

    // prologue: stage kt0 -> buf0, drain, publish
    STAGE_A128(0, 0);
    STAGE_B128(0, 0);
    asm volatile("s_waitcnt vmcnt(0)" ::: "memory");
    __builtin_amdgcn_sched_barrier(0);
    __builtin_amdgcn_s_barrier();
    __builtin_amdgcn_sched_barrier(0);

    i32x4 af[4], bf[4];

#pragma unroll 1
    for (int kt = 0; kt < NT; ++kt) {
      const int buf = kt & 1;
      const int kn = (kt + 1 < NT) ? kt + 1 : NT - 1;  // tail: harmless dummy
      STAGE_A128(kn, buf ^ 1);
      STAGE_B128(kn, buf ^ 1);
      if (run) {
        const int bb = buf * 32768;
        // sub 0: kc = lr (k 0..63)
        #pragma unroll
        for (int i_ = 0; i_ < 4; ++i_) {
          af[i_] = *(const i32x4*)(smem + bb + lr * 2048 + afix + i_ * 256);
          bf[i_] = *(const i32x4*)(smem + bb + lr * 2048 + bfix + i_ * 256);
        }
        __builtin_amdgcn_s_setprio(1);
        #pragma unroll
        for (int m_ = 0; m_ < 4; ++m_)
          #pragma unroll
          for (int n_ = 0; n_ < 4; ++n_)
            acc[m_][n_] = __builtin_amdgcn_mfma_i32_16x16x64_i8(
                af[m_], bf[n_], acc[m_][n_], 0, 0, 0);
        __builtin_amdgcn_s_setprio(0);
        // sub 1: kc = 4 + lr (k 64..127)
        #pragma unroll
        for (int i_ = 0; i_ < 4; ++i_) {
          af[i_] = *(const i32x4*)(smem + bb + 8192 + lr * 2048 + afix + i_ * 256);
          bf[i_] = *(const i32x4*)(smem + bb + 8192 + lr * 2048 + bfix + i_ * 256);
        }
        __builtin_amdgcn_s_setprio(1);
        #pragma unroll
        for (int m_ = 0; m_ < 4; ++m_)
          #pragma unroll
          for (int n_ = 0; n_ < 4; ++n_)
            acc[m_][n_] = __builtin_amdgcn_mfma_i32_16x16x64_i8(
                af[m_], bf[n_], acc[m_][n_], 0, 0, 0);
        __builtin_amdgcn_s_setprio(0);
      }
      asm volatile("s_waitcnt vmcnt(0)" ::: "memory");
      __builtin_amdgcn_sched_barrier(0);
      __builtin_amdgcn_s_barrier();
      __builtin_amdgcn_sched_barrier(0);
    }
  }

  // epilogue: C/D map col(n)=lane&15, row(m)=(lane>>4)*4+reg.
  // slot -> co via perm; skipped/padded rows carry exact zeros.
  const int* perm = meta + 1;
  #pragma unroll
  for (int m = 0; m < 4; ++m) {
    const int slotb = by * 128 + wm * 64 + m * 16 + lr * 4;
    const int c0 = perm[slotb], c1 = perm[slotb + 1];
    const int c2 = perm[slotb + 2], c3 = perm[slotb + 3];
    const int cos[4] = {c0, c1, c2, c3};
    #pragma unroll
    for (int nf = 0; nf < 4; ++nf) {
      const int col = wn * 64 + nf * 16 + lc;
      const int h = h0 + (col >> 6);
      const int w = col & 63;
      if (w < Ww) {
        #pragma unroll
        for (int r = 0; r < 4; ++r)
          out[(((size_t)b * COUT + cos[r]) * Hh + h) * Ww + w] =
              (float)acc[m][nf][r] * QINV;
      }
    }
  }
}

// ---- fallback: proven-correct naive direct conv (used only if ws too small)
__global__ __launch_bounds__(256) void binconv_naive(
    const float* __restrict__ x,
    const float* __restrict__ wgt,
    const float* __restrict__ mask,
    float* __restrict__ out) {
  const int w  = threadIdx.x;
  const int h  = blockIdx.x * 4 + threadIdx.y;
  const int co = blockIdx.y;
  const int b  = blockIdx.z;

  const float m = mask[co];
  const float scale = (m > 0.f) ? 1.f : ((m < 0.f) ? 0.f : 0.5f);

  const size_t obase = (((size_t)b * COUT + co) * Hh + h) * Ww + w;
  if (scale == 0.f) {
    if (w < Ww) out[obase] = 0.f;
    return;
  }

  const float* __restrict__ xb = x   + (size_t)b  * CIN * Hh * Ww;
  const float* __restrict__ wc = wgt + (size_t)co * CIN * 9;

  float acc = 0.f;
  for (int ci = 0; ci < CIN; ++ci) {
    const float* __restrict__ xc = xb + (size_t)ci * (Hh * Ww);
    const float* __restrict__ wk = wc + ci * 9;
    float wv[9];
    #pragma unroll
    for (int t2 = 0; t2 < 9; ++t2) wv[t2] = wk[t2];
    #pragma unroll
    for (int kh = 0; kh < 3; ++kh) {
      const int hh = h + kh - 1;
      if (hh < 0 || hh >= Hh) continue;
      const float* __restrict__ xr = xc + hh * Ww;
      #pragma unroll
      for (int kw = 0; kw < 3; ++kw) {
        const int ww = w + kw - 1;
        float xv = (ww >= 0 && ww < Ww) ? xr[ww] : 0.f;
        float s = (xv > 0.f) ? 1.f : ((xv < 0.f) ? -1.f : 0.f);
        acc += s * wv[kh * 3 + kw];
      }
    }
  }
  if (w < Ww) out[obase] = acc * scale;
}

extern "C" void kernel_launch(void* const* d_in, const int* in_sizes, int n_in,
                              void* d_out, int out_size, void* d_ws, size_t ws_size,
                              hipStream_t stream) {
  const float* x    = (const float*)d_in[0];
  const float* wgt  = (const float*)d_in[1];
  const float* mask = (const float*)d_in[2];
  float* out = (float*)d_out;

  bool ok = ws_size >= WS_REQUIRED;
  if (ok) {
    hipError_t e = hipFuncSetAttribute(
        (const void*)gemm_i8k, hipFuncAttributeMaxDynamicSharedMemorySize,
        65536);
    ok = (e == hipSuccess);
  }
  if (!ok) {
    hipLaunchKernelGGL(binconv_naive, dim3(Hh / 4, COUT, B_), dim3(64, 4, 1),
                       0, stream, x, wgt, mask, out);
    return;
  }

  signed char* xp8 = (signed char*)d_ws;
  signed char* awt = (signed char*)d_ws + AWT_OFF;
  int* meta        = (int*)((char*)d_ws + META_OFF);

  hipLaunchKernelGGL(prep_all, dim3(HP * B_ + 256), dim3(256), 0, stream,
                     x, wgt, mask, meta, awt, xp8);
  hipLaunchKernelGGL(gemm_i8k, dim3(896, 2), dim3(256), 65536, stream,
                     xp8, awt, meta, out);
}

// Round 20
// 104.028 us; speedup vs baseline: 1.2036x; 1.1086x over previous
//
#include <hip/hip_runtime.h>

#define B_    32
#define CIN   256
#define COUT  256
#define Hh    56
#define Ww    56
#define HP    58
#define WP    58
#define Kk    2304   // 9 taps * 256 ci
#define NT    18     // K-tiles of BK=128 (2 per tap)

#define QSCALE 2016.0f
#define QINV   (1.0f/2016.0f)

#define XPAD_BYTES ((size_t)B_*HP*WP*CIN)     // 27,557,888 i8 (ci-slot swizzled)
#define XPAD_GUARD 4096                        // row-overrun guard (reads only)
#define AWT_OFF    (XPAD_BYTES + XPAD_GUARD)
#define AWT_BYTES  ((size_t)NT*32768)          // weights tiled [kt][kc8][slot][16]
#define META_OFF   (AWT_OFF + AWT_BYTES)
#define WS_REQUIRED (META_OFF + 1040)

#define BLDS 32768                             // B resident base in LDS
#define LDS_TOTAL (32768 + 90112)              // A dbuf 32KB + B 88KB

typedef __attribute__((ext_vector_type(4))) int i32x4;

__device__ __forceinline__ void gload_lds16(const void* g, void* l) {
  __builtin_amdgcn_global_load_lds(
      (const __attribute__((address_space(1))) unsigned int*)g,
      (__attribute__((address_space(3))) unsigned int*)l, 16, 0, 0);
}

// ---- fused prepass: blocks [0, HP*B_) sign+pad+transpose+SWIZZLE x;
// blocks [HP*B_, +256) mask-scan + gated-weight quant (slot-tiled, BK=128).
// xpad layout: [b][hp][wp][ci-swizzled]: byte at (wp, slot_p*16+b4) holds
// value of logical ci = (slot_p ^ (wp&15))*16 + b4  (involution).
__global__ __launch_bounds__(256) void prep_all(
    const float* __restrict__ x,
    const float* __restrict__ wgt,
    const float* __restrict__ mask,
    int* __restrict__ meta,
    signed char* __restrict__ awt,
    signed char* __restrict__ xp) {
  const int t = threadIdx.x;
  const int bid = blockIdx.x;
  if (bid < HP * B_) {
    const int hp = bid % HP, b = bid / HP;
    unsigned* orow = (unsigned*)(xp + (size_t)(b * HP + hp) * WP * CIN);
    if (hp == 0 || hp == HP - 1) {
      for (int i = t; i < WP * CIN / 4; i += 256) orow[i] = 0u;
      return;
    }
    __shared__ __align__(16) signed char tile[WP * CIN];
    const int h = hp - 1;
    tile[t] = 0;
    tile[(WP - 1) * CIN + t] = 0;
    const int tx = t & 63, ty = t >> 6;
    if (tx < Ww) {
      const float* xr = x + ((size_t)b * CIN * Hh + h) * Ww;
      for (int ci = ty; ci < CIN; ci += 4) {
        float xv = xr[(size_t)ci * Hh * Ww + tx];
        tile[(1 + tx) * CIN + ci] = (xv > 0.f) ? 1 : (xv < 0.f ? -1 : 0);
      }
    }
    __syncthreads();
    for (int i = t; i < WP * CIN / 4; i += 256) {
      const int byte = i * 4;
      const int wp = byte >> 8;
      const int slot_p = (byte >> 4) & 15;
      const int slot_l = slot_p ^ (wp & 15);
      orow[i] = *(const unsigned*)&tile[wp * CIN + slot_l * 16 + (byte & 15)];
    }
  } else {
    __shared__ int sc[256];
    __shared__ int sperm[256];
    const int fl = (mask[t] >= 0.0f) ? 1 : 0;   // scale!=0 iff mask>=0
    sc[t] = fl;
    __syncthreads();
    for (int off = 1; off < 256; off <<= 1) {
      int v = sc[t];
      int u = (t >= off) ? sc[t - off] : 0;
      __syncthreads();
      sc[t] = v + u;
      __syncthreads();
    }
    const int incl = sc[t], act = sc[255];
    const int pos = fl ? (incl - 1) : (act + t - incl);
    sperm[pos] = t;
    __syncthreads();
    const int slot = bid - HP * B_;
    if (slot == 0) {
      meta[1 + pos] = t;
      if (t == 0) meta[0] = act;
    }
    const int co = sperm[slot];
    const float m = mask[co];
    const float scl = (m > 0.f ? 1.f : (m < 0.f ? 0.f : 0.5f)) * QSCALE;
    const float* wc = wgt + (size_t)co * Kk;     // [ci][tap]
    for (int o = t; o < Kk; o += 256) {
      int tap = o >> 8, ci = o & 255;
      int q = __float2int_rn(wc[ci * 9 + tap] * scl);
      int kt = tap * 2 + (ci >> 7);              // BK=128 K-tile
      int kk = ci & 127;
      awt[((size_t)kt * 2048 + (kk >> 4) * 256 + slot) * 16 + (kk & 15)] =
          (signed char)q;
    }
  }
}

// ---- main: compacted-M i8 GEMM with RESIDENT B. Block = 128 slots (by
// half) x 256 n (4 output rows x 64 w). 8 waves (2M x 4N) of 64x64,
// acc[4][4]=64 AGPR. LDS: A dbuf 2x16KB @0 + B resident 88KB @32768
// (6 hp-rows x 58 x 256, ci-slot swizzled) = 120KB -> 1 block/CU.
// B staged ONCE (11 DMA/thread); per KT only A is staged (2 DMA/thread,
// 16KB) -> DMA wall (the measured ~10B/cyc/CU gload_lds limit) drops 2-4x.
// All 18 KTs read B-fragments at (kh,kw)-shifted, slot-XOR'd offsets.
// grid=(448 = b*14 + hblk, 2), block=512
__global__ __launch_bounds__(512, 2) void gemm_i8rb(
    const signed char* __restrict__ xp,
    const signed char* __restrict__ awt,
    const int* __restrict__ meta,
    float* __restrict__ out) {
  extern __shared__ char smem[];

  const int t = threadIdx.x;
  const int nb = blockIdx.x, by = blockIdx.y;
  const int b = nb / 14, h0 = (nb % 14) * 4;

  const int act = meta[0];
  const int rem = act - by * 128;
  const int ng = (rem <= 0) ? 0 : ((rem > 64) ? 2 : 1);

  const int wid = t >> 6, lane = t & 63;
  const int wm = wid >> 2, wn = wid & 3;     // 2M x 4N waves of 64x64
  const int lc = lane & 15, lr = lane >> 4;

  i32x4 acc[4][4] = {};

  if (ng > 0) {
    // A staging: 2 loads/thread/KT cover [8kc][128 slot][16] = 16KB
    const signed char* awp =
        awt + by * 2048 + (t >> 7) * 4096 + (t & 127) * 16;
    char* dA = smem + t * 16;
    // B resident staging: linear copy of 6 rows (88KB) from swizzled xpad
    const signed char* xsrc = xp + ((size_t)b * HP + h0) * WP * CIN;
    char* dB = smem + BLDS + t * 16;

#define STAGE_A128(ktx, BUF) do {                                              \
    const signed char* s_ = awp + (size_t)(ktx) * 32768;                       \
    gload_lds16(s_,         dA + (BUF) * 16384);                               \
    gload_lds16(s_ + 16384, dA + (BUF) * 16384 + 8192);                        \
  } while (0)

    // prologue: B resident (11 loads) + A kt0 -> buf0
    #pragma unroll
    for (int j = 0; j < 11; ++j)
      gload_lds16(xsrc + t * 16 + j * 8192, dB + j * 8192);
    STAGE_A128(0, 0);
    asm volatile("s_waitcnt vmcnt(0)" ::: "memory");
    __builtin_amdgcn_sched_barrier(0);
    __builtin_amdgcn_s_barrier();
    __builtin_amdgcn_sched_barrier(0);

    const int afix = (wm * 64 + lc) * 16;    // + buf*16384 + (s*4+lr)*2048 + m*256
    const bool run = (wm < ng);
    i32x4 af[4], bf[4];

#pragma unroll 1
    for (int kt = 0; kt < NT; ++kt) {
      const int buf = kt & 1;
      const int kn = (kt + 1 < NT) ? kt + 1 : NT - 1;  // tail: harmless dummy
      STAGE_A128(kn, buf ^ 1);
      if (run) {
        const int tap = kt >> 1;
        const int kh = tap / 3, kw = tap - kh * 3;
        const int kbit = (kt & 1) * 8;
        // B row base for this wave/tap: row = wn + kh
        const int brow = BLDS + ((wn + kh) * WP) * 256;
        #pragma unroll
        for (int s = 0; s < 2; ++s) {
          const int kc = s * 4 + lr;
          #pragma unroll
          for (int m_ = 0; m_ < 4; ++m_)
            af[m_] = *(const i32x4*)(smem + buf * 16384 + kc * 2048 +
                                     afix + m_ * 256);
          const int sl = kbit + kc;
          #pragma unroll
          for (int nf = 0; nf < 4; ++nf) {
            const int wp = kw + nf * 16 + lc;
            bf[nf] = *(const i32x4*)(smem + brow + wp * 256 +
                                     ((sl ^ (wp & 15)) << 4));
          }
          __builtin_amdgcn_s_setprio(1);
          #pragma unroll
          for (int m_ = 0; m_ < 4; ++m_)
            #pragma unroll
            for (int n_ = 0; n_ < 4; ++n_)
              acc[m_][n_] = __builtin_amdgcn_mfma_i32_16x16x64_i8(
                  af[m_], bf[n_], acc[m_][n_], 0, 0, 0);
          __builtin_amdgcn_s_setprio(0);
        }
      }
      asm volatile("s_waitcnt vmcnt(0)" ::: "memory");
      __builtin_amdgcn_sched_barrier(0);
      __builtin_amdgcn_s_barrier();
      __builtin_amdgcn_sched_barrier(0);
    }
  }

  // epilogue: C/D map col(n)=lane&15, row(m)=(lane>>4)*4+reg.
  // wave covers h = h0 + wn, w = nf*16 + lc. slot -> co via perm.
  const int* perm = meta + 1;
  const int h = h0 + wn;
  #pragma unroll
  for (int m = 0; m < 4; ++m) {
    const int slotb = by * 128 + wm * 64 + m * 16 + lr * 4;
    const int c0 = perm[slotb], c1 = perm[slotb + 1];
    const int c2 = perm[slotb + 2], c3 = perm[slotb + 3];
    const int cos[4] = {c0, c1, c2, c3};
    #pragma unroll
    for (int nf = 0; nf < 4; ++nf) {
      const int w = nf * 16 + lc;
      if (w < Ww) {
        #pragma unroll
        for (int r = 0; r < 4; ++r)
          out[(((size_t)b * COUT + cos[r]) * Hh + h) * Ww + w] =
              (float)acc[m][nf][r] * QINV;
      }
    }
  }
}

// ---- fallback: proven-correct naive direct conv (used only if ws too small)
__global__ __launch_bounds__(256) void binconv_naive(
    const float* __restrict__ x,
    const float* __restrict__ wgt,
    const float* __restrict__ mask,
    float* __restrict__ out) {
  const int w  = threadIdx.x;
  const int h  = blockIdx.x * 4 + threadIdx.y;
  const int co = blockIdx.y;
  const int b  = blockIdx.z;

  const float m = mask[co];
  const float scale = (m > 0.f) ? 1.f : ((m < 0.f) ? 0.f : 0.5f);

  const size_t obase = (((size_t)b * COUT + co) * Hh + h) * Ww + w;
  if (scale == 0.f) {
    if (w < Ww) out[obase] = 0.f;
    return;
  }

  const float* __restrict__ xb = x   + (size_t)b  * CIN * Hh * Ww;
  const float* __restrict__ wc = wgt + (size_t)co * CIN * 9;

  float acc = 0.f;
  for (int ci = 0; ci < CIN; ++ci) {
    const float* __restrict__ xc = xb + (size_t)ci * (Hh * Ww);
    const float* __restrict__ wk = wc + ci * 9;
    float wv[9];
    #pragma unroll
    for (int t2 = 0; t2 < 9; ++t2) wv[t2] = wk[t2];
    #pragma unroll
    for (int kh = 0; kh < 3; ++kh) {
      const int hh = h + kh - 1;
      if (hh < 0 || hh >= Hh) continue;
      const float* __restrict__ xr = xc + hh * Ww;
      #pragma unroll
      for (int kw = 0; kw < 3; ++kw) {
        const int ww = w + kw - 1;
        float xv = (ww >= 0 && ww < Ww) ? xr[ww] : 0.f;
        float s = (xv > 0.f) ? 1.f : ((xv < 0.f) ? -1.f : 0.f);
        acc += s * wv[kh * 3 + kw];
      }
    }
  }
  if (w < Ww) out[obase] = acc * scale;
}

extern "C" void kernel_launch(void* const* d_in, const int* in_sizes, int n_in,
                              void* d_out, int out_size, void* d_ws, size_t ws_size,
                              hipStream_t stream) {
  const float* x    = (const float*)d_in[0];
  const float* wgt  = (const float*)d_in[1];
  const float* mask = (const float*)d_in[2];
  float* out = (float*)d_out;

  bool ok = ws_size >= WS_REQUIRED;
  if (ok) {
    hipError_t e = hipFuncSetAttribute(
        (const void*)gemm_i8rb, hipFuncAttributeMaxDynamicSharedMemorySize,
        LDS_TOTAL);
    ok = (e == hipSuccess);
  }
  if (!ok) {
    hipLaunchKernelGGL(binconv_naive, dim3(Hh / 4, COUT, B_), dim3(64, 4, 1),
                       0, stream, x, wgt, mask, out);
    return;
  }

  signed char* xp8 = (signed char*)d_ws;
  signed char* awt = (signed char*)d_ws + AWT_OFF;
  int* meta        = (int*)((char*)d_ws + META_OFF);

  hipLaunchKernelGGL(prep_all, dim3(HP * B_ + 256), dim3(256), 0, stream,
                     x, wgt, mask, meta, awt, xp8);
  hipLaunchKernelGGL(gemm_i8rb, dim3(448, 2), dim3(512), LDS_TOTAL, stream,
                     xp8, awt, meta, out);
}

// Round 21
// 103.573 us; speedup vs baseline: 1.2089x; 1.0044x over previous
//
#include <hip/hip_runtime.h>

#define B_    32
#define CIN   256
#define COUT  256
#define Hh    56
#define Ww    56
#define HP    58
#define WP    58
#define Kk    2304   // 9 taps * 256 ci
#define NT    18     // K-tiles of BK=128 (2 per tap)

#define QSCALE 2016.0f
#define QINV   (1.0f/2016.0f)

#define XPAD_BYTES ((size_t)B_*HP*WP*CIN)     // 27,557,888 i8 (ci-slot swizzled)
#define XPAD_GUARD 16384                       // B-slab over-read guard
#define AWT_OFF    (XPAD_BYTES + XPAD_GUARD)
#define AWT_BYTES  ((size_t)NT*32768)          // weights tiled [kt][kc8][slot][16]
#define META_OFF   (AWT_OFF + AWT_BYTES)
#define WS_REQUIRED (META_OFF + 1040)

#define ABUFS 49152                            // A tri-buffer: 3 x 16KB
#define BLDS  ABUFS                            // B slab base in LDS
#define LDS_TOTAL (ABUFS + 98304)              // 48KB + 96KB = 144KB

typedef __attribute__((ext_vector_type(4))) int i32x4;

__device__ __forceinline__ void gload_lds16(const void* g, void* l) {
  __builtin_amdgcn_global_load_lds(
      (const __attribute__((address_space(1))) unsigned int*)g,
      (__attribute__((address_space(3))) unsigned int*)l, 16, 0, 0);
}

// ---- fused prepass: blocks [0, HP*B_) sign+pad+transpose+SWIZZLE x;
// blocks [HP*B_, +256) mask-scan + gated-weight quant (slot-tiled, BK=128).
// xpad layout: [b][hp][wp][ci-swizzled]: byte at (wp, slot_p*16+b4) holds
// value of logical ci = (slot_p ^ (wp&15))*16 + b4  (involution).
__global__ __launch_bounds__(256) void prep_all(
    const float* __restrict__ x,
    const float* __restrict__ wgt,
    const float* __restrict__ mask,
    int* __restrict__ meta,
    signed char* __restrict__ awt,
    signed char* __restrict__ xp) {
  const int t = threadIdx.x;
  const int bid = blockIdx.x;
  if (bid < HP * B_) {
    const int hp = bid % HP, b = bid / HP;
    unsigned* orow = (unsigned*)(xp + (size_t)(b * HP + hp) * WP * CIN);
    if (hp == 0 || hp == HP - 1) {
      for (int i = t; i < WP * CIN / 4; i += 256) orow[i] = 0u;
      return;
    }
    __shared__ __align__(16) signed char tile[WP * CIN];
    const int h = hp - 1;
    tile[t] = 0;
    tile[(WP - 1) * CIN + t] = 0;
    const int tx = t & 63, ty = t >> 6;
    if (tx < Ww) {
      const float* xr = x + ((size_t)b * CIN * Hh + h) * Ww;
      for (int ci = ty; ci < CIN; ci += 4) {
        float xv = xr[(size_t)ci * Hh * Ww + tx];
        tile[(1 + tx) * CIN + ci] = (xv > 0.f) ? 1 : (xv < 0.f ? -1 : 0);
      }
    }
    __syncthreads();
    for (int i = t; i < WP * CIN / 4; i += 256) {
      const int byte = i * 4;
      const int wp = byte >> 8;
      const int slot_p = (byte >> 4) & 15;
      const int slot_l = slot_p ^ (wp & 15);
      orow[i] = *(const unsigned*)&tile[wp * CIN + slot_l * 16 + (byte & 15)];
    }
  } else {
    __shared__ int sc[256];
    __shared__ int sperm[256];
    const int fl = (mask[t] >= 0.0f) ? 1 : 0;   // scale!=0 iff mask>=0
    sc[t] = fl;
    __syncthreads();
    for (int off = 1; off < 256; off <<= 1) {
      int v = sc[t];
      int u = (t >= off) ? sc[t - off] : 0;
      __syncthreads();
      sc[t] = v + u;
      __syncthreads();
    }
    const int incl = sc[t], act = sc[255];
    const int pos = fl ? (incl - 1) : (act + t - incl);
    sperm[pos] = t;
    __syncthreads();
    const int slot = bid - HP * B_;
    if (slot == 0) {
      meta[1 + pos] = t;
      if (t == 0) meta[0] = act;
    }
    const int co = sperm[slot];
    const float m = mask[co];
    const float scl = (m > 0.f ? 1.f : (m < 0.f ? 0.f : 0.5f)) * QSCALE;
    const float* wc = wgt + (size_t)co * Kk;     // [ci][tap]
    for (int o = t; o < Kk; o += 256) {
      int tap = o >> 8, ci = o & 255;
      int q = __float2int_rn(wc[ci * 9 + tap] * scl);
      int kt = tap * 2 + (ci >> 7);              // BK=128 K-tile
      int kk = ci & 127;
      awt[((size_t)kt * 2048 + (kk >> 4) * 256 + slot) * 16 + (kk & 15)] =
          (signed char)q;
    }
  }
}

// ---- main: compacted-M i8 GEMM, RESIDENT B, 16 waves (4 waves/SIMD).
// Block = 128 slots (by half) x 256 n (4 output rows x 64 w). 16 waves
// (4M x 4N) of 32x64, acc[2][4]=32 AGPR, ~90 regs (cap 128 via
// __launch_bounds__(1024,4)). LDS: A tri-buffer 3x16KB @0 + B slab 96KB
// @49152 = 144KB -> 1 block/CU = 16 waves/CU. B staged ONCE (6 linear
// loads/thread); per KT one A-load/thread with depth-2 counted vmcnt(1).
// grid=(448 = b*14 + hblk, 2), block=1024
__global__ __launch_bounds__(1024, 4) void gemm_i8w(
    const signed char* __restrict__ xp,
    const signed char* __restrict__ awt,
    const int* __restrict__ meta,
    float* __restrict__ out) {
  extern __shared__ char smem[];

  const int t = threadIdx.x;
  const int nb = blockIdx.x, by = blockIdx.y;
  const int b = nb / 14, h0 = (nb % 14) * 4;

  const int act = meta[0];
  const int rem = act - by * 128;
  const int g32 = (rem <= 0) ? 0 : ((rem >= 128) ? 4 : ((rem + 31) >> 5));

  const int wid = t >> 6, lane = t & 63;
  const int wm = wid >> 2, wn = wid & 3;     // 4M x 4N waves of 32x64
  const int lc = lane & 15, lr = lane >> 4;

  i32x4 acc[2][4] = {};

  if (g32 > 0) {
    // A staging: 1 load/thread covers [8kc][128 slot][16] = 16KB
    const signed char* awp =
        awt + by * 2048 + (size_t)(t >> 7) * 4096 + (t & 127) * 16;
    char* dA = smem + t * 16;
    // B slab: 6 linear loads/thread (96KB; reads rows h0..h0+6.6, guard ok)
    const signed char* xsrc = xp + ((size_t)b * HP + h0) * WP * CIN;
    char* dB = smem + BLDS + t * 16;

#define STAGE_A128(ktx, BO)                                                    \
    gload_lds16(awp + (size_t)(ktx) * 32768, dA + (BO))

    // prologue: B slab + A kt0 -> buf0 + A kt1 -> buf1; keep only A(kt1)
    #pragma unroll
    for (int j = 0; j < 6; ++j)
      gload_lds16(xsrc + t * 16 + j * 16384, dB + j * 16384);
    STAGE_A128(0, 0);
    STAGE_A128(1, 16384);
    asm volatile("s_waitcnt vmcnt(1)" ::: "memory");
    __builtin_amdgcn_sched_barrier(0);
    __builtin_amdgcn_s_barrier();
    __builtin_amdgcn_sched_barrier(0);

    const int afix = (wm * 32 + lc) * 16;    // + rb + kc*2048 + m*256
    const bool run = (wm < g32);
    int rb = 0, rbn = 16384, sb = 32768;
    i32x4 af[2], bf[4];

#pragma unroll 1
    for (int kt = 0; kt < NT; ++kt) {
      const int kn = (kt + 2 < NT) ? kt + 2 : NT - 1;  // tail: harmless dummy
      STAGE_A128(kn, sb);
      if (run) {
        const int tap = kt >> 1;
        const int kh = tap / 3, kw = tap - kh * 3;
        const int kbit = (kt & 1) * 8;
        const int brow = BLDS + ((wn + kh) * WP) * 256;
        #pragma unroll
        for (int s = 0; s < 2; ++s) {
          const int kc = s * 4 + lr;
          #pragma unroll
          for (int m_ = 0; m_ < 2; ++m_)
            af[m_] = *(const i32x4*)(smem + rb + kc * 2048 + afix + m_ * 256);
          const int sl = kbit + kc;
          #pragma unroll
          for (int nf = 0; nf < 4; ++nf) {
            const int wp = kw + nf * 16 + lc;
            bf[nf] = *(const i32x4*)(smem + brow + wp * 256 +
                                     ((sl ^ (wp & 15)) << 4));
          }
          __builtin_amdgcn_s_setprio(1);
          #pragma unroll
          for (int m_ = 0; m_ < 2; ++m_)
            #pragma unroll
            for (int n_ = 0; n_ < 4; ++n_)
              acc[m_][n_] = __builtin_amdgcn_mfma_i32_16x16x64_i8(
                  af[m_], bf[n_], acc[m_][n_], 0, 0, 0);
          __builtin_amdgcn_s_setprio(0);
        }
      }
      // drain A(kt+1) (issued last iter), keep this iter's A(kt+2)
      asm volatile("s_waitcnt vmcnt(1)" ::: "memory");
      __builtin_amdgcn_sched_barrier(0);
      __builtin_amdgcn_s_barrier();
      __builtin_amdgcn_sched_barrier(0);
      int tmp_ = rb; rb = rbn; rbn = sb; sb = tmp_;
    }
    asm volatile("s_waitcnt vmcnt(0)" ::: "memory");  // drain tail dummies
  }

  // epilogue: C/D map col(n)=lane&15, row(m)=(lane>>4)*4+reg.
  // wave covers h = h0 + wn, w = nf*16 + lc. slot -> co via perm.
  const int* perm = meta + 1;
  const int h = h0 + wn;
  #pragma unroll
  for (int m = 0; m < 2; ++m) {
    const int slotb = by * 128 + wm * 32 + m * 16 + lr * 4;
    const int c0 = perm[slotb], c1 = perm[slotb + 1];
    const int c2 = perm[slotb + 2], c3 = perm[slotb + 3];
    const int cos[4] = {c0, c1, c2, c3};
    #pragma unroll
    for (int nf = 0; nf < 4; ++nf) {
      const int w = nf * 16 + lc;
      if (w < Ww) {
        #pragma unroll
        for (int r = 0; r < 4; ++r)
          out[(((size_t)b * COUT + cos[r]) * Hh + h) * Ww + w] =
              (float)acc[m][nf][r] * QINV;
      }
    }
  }
}

// ---- fallback: proven-correct naive direct conv (used only if ws too small)
__global__ __launch_bounds__(256) void binconv_naive(
    const float* __restrict__ x,
    const float* __restrict__ wgt,
    const float* __restrict__ mask,
    float* __restrict__ out) {
  const int w  = threadIdx.x;
  const int h  = blockIdx.x * 4 + threadIdx.y;
  const int co = blockIdx.y;
  const int b  = blockIdx.z;

  const float m = mask[co];
  const float scale = (m > 0.f) ? 1.f : ((m < 0.f) ? 0.f : 0.5f);

  const size_t obase = (((size_t)b * COUT + co) * Hh + h) * Ww + w;
  if (scale == 0.f) {
    if (w < Ww) out[obase] = 0.f;
    return;
  }

  const float* __restrict__ xb = x   + (size_t)b  * CIN * Hh * Ww;
  const float* __restrict__ wc = wgt + (size_t)co * CIN * 9;

  float acc = 0.f;
  for (int ci = 0; ci < CIN; ++ci) {
    const float* __restrict__ xc = xb + (size_t)ci * (Hh * Ww);
    const float* __restrict__ wk = wc + ci * 9;
    float wv[9];
    #pragma unroll
    for (int t2 = 0; t2 < 9; ++t2) wv[t2] = wk[t2];
    #pragma unroll
    for (int kh = 0; kh < 3; ++kh) {
      const int hh = h + kh - 1;
      if (hh < 0 || hh >= Hh) continue;
      const float* __restrict__ xr = xc + hh * Ww;
      #pragma unroll
      for (int kw = 0; kw < 3; ++kw) {
        const int ww = w + kw - 1;
        float xv = (ww >= 0 && ww < Ww) ? xr[ww] : 0.f;
        float s = (xv > 0.f) ? 1.f : ((xv < 0.f) ? -1.f : 0.f);
        acc += s * wv[kh * 3 + kw];
      }
    }
  }
  if (w < Ww) out[obase] = acc * scale;
}

extern "C" void kernel_launch(void* const* d_in, const int* in_sizes, int n_in,
                              void* d_out, int out_size, void* d_ws, size_t ws_size,
                              hipStream_t stream) {
  const float* x    = (const float*)d_in[0];
  const float* wgt  = (const float*)d_in[1];
  const float* mask = (const float*)d_in[2];
  float* out = (float*)d_out;

  bool ok = ws_size >= WS_REQUIRED;
  if (ok) {
    hipError_t e = hipFuncSetAttribute(
        (const void*)gemm_i8w, hipFuncAttributeMaxDynamicSharedMemorySize,
        LDS_TOTAL);
    ok = (e == hipSuccess);
  }
  if (!ok) {
    hipLaunchKernelGGL(binconv_naive, dim3(Hh / 4, COUT, B_), dim3(64, 4, 1),
                       0, stream, x, wgt, mask, out);
    return;
  }

  signed char* xp8 = (signed char*)d_ws;
  signed char* awt = (signed char*)d_ws + AWT_OFF;
  int* meta        = (int*)((char*)d_ws + META_OFF);

  hipLaunchKernelGGL(prep_all, dim3(HP * B_ + 256), dim3(256), 0, stream,
                     x, wgt, mask, meta, awt, xp8);
  hipLaunchKernelGGL(gemm_i8w, dim3(448, 2), dim3(1024), LDS_TOTAL, stream,
                     xp8, awt, meta, out);
}

// Round 22
// 77.653 us; speedup vs baseline: 1.6124x; 1.3338x over previous
//
#include <hip/hip_runtime.h>

#define B_    32
#define CIN   256
#define COUT  256
#define Hh    56
#define Ww    56
#define HP    58
#define WP    58
#define Kk    2304   // 9 taps * 256 ci
#define NT    18     // K-tiles of BK=128 (2 per tap)

#define QSCALE 2016.0f
#define QINV   (1.0f/2016.0f)

#define XPAD_BYTES ((size_t)B_*HP*WP*CIN)     // 27,557,888 i8 (ci-slot swizzled)
#define XPAD_GUARD 16384                       // B-slab over-read guard
#define AWT_OFF    (XPAD_BYTES + XPAD_GUARD)
#define AWT_BYTES  ((size_t)NT*32768)          // weights tiled [kt][kc8][slot][16]
#define META_OFF   (AWT_OFF + AWT_BYTES)
#define WS_REQUIRED (META_OFF + 1040)

#define ABUFS 49152                            // A tri-buffer: 3 x 16KB
#define BLDS  ABUFS                            // B slab base in LDS
#define LDS_TOTAL (ABUFS + 98304)              // 48KB + 96KB = 144KB

#define TP 260                                 // padded tile row stride (bytes)

typedef __attribute__((ext_vector_type(4))) int i32x4;

__device__ __forceinline__ void gload_lds16(const void* g, void* l) {
  __builtin_amdgcn_global_load_lds(
      (const __attribute__((address_space(1))) unsigned int*)g,
      (__attribute__((address_space(3))) unsigned int*)l, 16, 0, 0);
}

// ---- fused prepass: blocks [0, HP*B_) sign+pad+transpose+SWIZZLE x;
// blocks [HP*B_, +256) mask-scan + gated-weight quant (slot-tiled, BK=128).
// xpad layout: [b][hp][wp][ci-swizzled]: byte at (wp, slot_p*16+b4) holds
// value of logical ci = (slot_p ^ (wp&15))*16 + b4  (involution).
// LDS tile rows padded to 260B: write addr/4 = (1+tx)*65 + ci/4 spreads all
// lanes across banks (was stride-256 -> full-wave same-bank conflict).
__global__ __launch_bounds__(256) void prep_all(
    const float* __restrict__ x,
    const float* __restrict__ wgt,
    const float* __restrict__ mask,
    int* __restrict__ meta,
    signed char* __restrict__ awt,
    signed char* __restrict__ xp) {
  const int t = threadIdx.x;
  const int bid = blockIdx.x;
  if (bid < HP * B_) {
    const int hp = bid % HP, b = bid / HP;
    unsigned* orow = (unsigned*)(xp + (size_t)(b * HP + hp) * WP * CIN);
    if (hp == 0 || hp == HP - 1) {
      for (int i = t; i < WP * CIN / 4; i += 256) orow[i] = 0u;
      return;
    }
    __shared__ __align__(16) signed char tile[WP * TP];
    const int h = hp - 1;
    tile[t] = 0;                               // wp=0 border (pad bytes unread)
    tile[(WP - 1) * TP + t] = 0;               // wp=57 border
    const int tx = t & 63, ty = t >> 6;
    if (tx < Ww) {
      const float* xr = x + ((size_t)b * CIN * Hh + h) * Ww;
      for (int ci0 = ty * 4; ci0 < CIN; ci0 += 16) {
        unsigned pk = 0;
        #pragma unroll
        for (int j = 0; j < 4; ++j) {
          float xv = xr[(size_t)(ci0 + j) * (Hh * Ww) + tx];
          unsigned s = (xv > 0.f) ? 1u : (xv < 0.f ? 0xFFu : 0u);
          pk |= s << (8 * j);
        }
        *(unsigned*)&tile[(1 + tx) * TP + ci0] = pk;
      }
    }
    __syncthreads();
    for (int i = t; i < WP * CIN / 4; i += 256) {
      const int byte = i * 4;
      const int wp = byte >> 8;
      const int slot_p = (byte >> 4) & 15;
      const int slot_l = slot_p ^ (wp & 15);
      orow[i] = *(const unsigned*)&tile[wp * TP + slot_l * 16 + (byte & 15)];
    }
  } else {
    __shared__ int sc[256];
    __shared__ int sperm[256];
    const int fl = (mask[t] >= 0.0f) ? 1 : 0;   // scale!=0 iff mask>=0
    sc[t] = fl;
    __syncthreads();
    for (int off = 1; off < 256; off <<= 1) {
      int v = sc[t];
      int u = (t >= off) ? sc[t - off] : 0;
      __syncthreads();
      sc[t] = v + u;
      __syncthreads();
    }
    const int incl = sc[t], act = sc[255];
    const int pos = fl ? (incl - 1) : (act + t - incl);
    sperm[pos] = t;
    __syncthreads();
    const int slot = bid - HP * B_;
    if (slot == 0) {
      meta[1 + pos] = t;
      if (t == 0) meta[0] = act;
    }
    const int co = sperm[slot];
    const float m = mask[co];
    const float scl = (m > 0.f ? 1.f : (m < 0.f ? 0.f : 0.5f)) * QSCALE;
    const float* wc = wgt + (size_t)co * Kk;     // [ci][tap]
    for (int o = t; o < Kk; o += 256) {
      int tap = o >> 8, ci = o & 255;
      int q = __float2int_rn(wc[ci * 9 + tap] * scl);
      int kt = tap * 2 + (ci >> 7);              // BK=128 K-tile
      int kk = ci & 127;
      awt[((size_t)kt * 2048 + (kk >> 4) * 256 + slot) * 16 + (kk & 15)] =
          (signed char)q;
    }
  }
}

// ---- main: compacted-M i8 GEMM, RESIDENT B, 16 waves (4 waves/SIMD).
// Block = 128 slots (by half) x 256 n (4 output rows x 64 w). 16 waves
// (4M x 4N) of 32x64, acc[2][4]=32 AGPR, ~90 regs (cap 128 via
// __launch_bounds__(1024,4)). LDS: A tri-buffer 3x16KB @0 + B slab 96KB
// @49152 = 144KB -> 1 block/CU = 16 waves/CU. B staged ONCE (6 linear
// loads/thread); per KT one A-load/thread with depth-2 counted vmcnt(1).
// grid=(448 = b*14 + hblk, 2), block=1024
__global__ __launch_bounds__(1024, 4) void gemm_i8w(
    const signed char* __restrict__ xp,
    const signed char* __restrict__ awt,
    const int* __restrict__ meta,
    float* __restrict__ out) {
  extern __shared__ char smem[];

  const int t = threadIdx.x;
  const int nb = blockIdx.x, by = blockIdx.y;
  const int b = nb / 14, h0 = (nb % 14) * 4;

  const int act = meta[0];
  const int rem = act - by * 128;
  const int g32 = (rem <= 0) ? 0 : ((rem >= 128) ? 4 : ((rem + 31) >> 5));

  const int wid = t >> 6, lane = t & 63;
  const int wm = wid >> 2, wn = wid & 3;     // 4M x 4N waves of 32x64
  const int lc = lane & 15, lr = lane >> 4;

  i32x4 acc[2][4] = {};

  if (g32 > 0) {
    // A staging: 1 load/thread covers [8kc][128 slot][16] = 16KB
    const signed char* awp =
        awt + by * 2048 + (size_t)(t >> 7) * 4096 + (t & 127) * 16;
    char* dA = smem + t * 16;
    // B slab: 6 linear loads/thread (96KB; reads rows h0..h0+6.6, guard ok)
    const signed char* xsrc = xp + ((size_t)b * HP + h0) * WP * CIN;
    char* dB = smem + BLDS + t * 16;

#define STAGE_A128(ktx, BO)                                                    \
    gload_lds16(awp + (size_t)(ktx) * 32768, dA + (BO))

    // prologue: B slab + A kt0 -> buf0 + A kt1 -> buf1; keep only A(kt1)
    #pragma unroll
    for (int j = 0; j < 6; ++j)
      gload_lds16(xsrc + t * 16 + j * 16384, dB + j * 16384);
    STAGE_A128(0, 0);
    STAGE_A128(1, 16384);
    asm volatile("s_waitcnt vmcnt(1)" ::: "memory");
    __builtin_amdgcn_sched_barrier(0);
    __builtin_amdgcn_s_barrier();
    __builtin_amdgcn_sched_barrier(0);

    const int afix = (wm * 32 + lc) * 16;    // + rb + kc*2048 + m*256
    const bool run = (wm < g32);
    int rb = 0, rbn = 16384, sb = 32768;
    i32x4 af[2], bf[4];

#pragma unroll 1
    for (int kt = 0; kt < NT; ++kt) {
      const int kn = (kt + 2 < NT) ? kt + 2 : NT - 1;  // tail: harmless dummy
      STAGE_A128(kn, sb);
      if (run) {
        const int tap = kt >> 1;
        const int kh = tap / 3, kw = tap - kh * 3;
        const int kbit = (kt & 1) * 8;
        const int brow = BLDS + ((wn + kh) * WP) * 256;
        #pragma unroll
        for (int s = 0; s < 2; ++s) {
          const int kc = s * 4 + lr;
          #pragma unroll
          for (int m_ = 0; m_ < 2; ++m_)
            af[m_] = *(const i32x4*)(smem + rb + kc * 2048 + afix + m_ * 256);
          const int sl = kbit + kc;
          #pragma unroll
          for (int nf = 0; nf < 4; ++nf) {
            const int wp = kw + nf * 16 + lc;
            bf[nf] = *(const i32x4*)(smem + brow + wp * 256 +
                                     ((sl ^ (wp & 15)) << 4));
          }
          __builtin_amdgcn_s_setprio(1);
          #pragma unroll
          for (int m_ = 0; m_ < 2; ++m_)
            #pragma unroll
            for (int n_ = 0; n_ < 4; ++n_)
              acc[m_][n_] = __builtin_amdgcn_mfma_i32_16x16x64_i8(
                  af[m_], bf[n_], acc[m_][n_], 0, 0, 0);
          __builtin_amdgcn_s_setprio(0);
        }
      }
      // drain A(kt+1) (issued last iter), keep this iter's A(kt+2)
      asm volatile("s_waitcnt vmcnt(1)" ::: "memory");
      __builtin_amdgcn_sched_barrier(0);
      __builtin_amdgcn_s_barrier();
      __builtin_amdgcn_sched_barrier(0);
      int tmp_ = rb; rb = rbn; rbn = sb; sb = tmp_;
    }
    asm volatile("s_waitcnt vmcnt(0)" ::: "memory");  // drain tail dummies
  }

  // epilogue: C/D map col(n)=lane&15, row(m)=(lane>>4)*4+reg.
  // wave covers h = h0 + wn, w = nf*16 + lc. slot -> co via perm.
  const int* perm = meta + 1;
  const int h = h0 + wn;
  #pragma unroll
  for (int m = 0; m < 2; ++m) {
    const int slotb = by * 128 + wm * 32 + m * 16 + lr * 4;
    const int c0 = perm[slotb], c1 = perm[slotb + 1];
    const int c2 = perm[slotb + 2], c3 = perm[slotb + 3];
    const int cos[4] = {c0, c1, c2, c3};
    #pragma unroll
    for (int nf = 0; nf < 4; ++nf) {
      const int w = nf * 16 + lc;
      if (w < Ww) {
        #pragma unroll
        for (int r = 0; r < 4; ++r)
          out[(((size_t)b * COUT + cos[r]) * Hh + h) * Ww + w] =
              (float)acc[m][nf][r] * QINV;
      }
    }
  }
}

// ---- fallback: proven-correct naive direct conv (used only if ws too small)
__global__ __launch_bounds__(256) void binconv_naive(
    const float* __restrict__ x,
    const float* __restrict__ wgt,
    const float* __restrict__ mask,
    float* __restrict__ out) {
  const int w  = threadIdx.x;
  const int h  = blockIdx.x * 4 + threadIdx.y;
  const int co = blockIdx.y;
  const int b  = blockIdx.z;

  const float m = mask[co];
  const float scale = (m > 0.f) ? 1.f : ((m < 0.f) ? 0.f : 0.5f);

  const size_t obase = (((size_t)b * COUT + co) * Hh + h) * Ww + w;
  if (scale == 0.f) {
    if (w < Ww) out[obase] = 0.f;
    return;
  }

  const float* __restrict__ xb = x   + (size_t)b  * CIN * Hh * Ww;
  const float* __restrict__ wc = wgt + (size_t)co * CIN * 9;

  float acc = 0.f;
  for (int ci = 0; ci < CIN; ++ci) {
    const float* __restrict__ xc = xb + (size_t)ci * (Hh * Ww);
    const float* __restrict__ wk = wc + ci * 9;
    float wv[9];
    #pragma unroll
    for (int t2 = 0; t2 < 9; ++t2) wv[t2] = wk[t2];
    #pragma unroll
    for (int kh = 0; kh < 3; ++kh) {
      const int hh = h + kh - 1;
      if (hh < 0 || hh >= Hh) continue;
      const float* __restrict__ xr = xc + hh * Ww;
      #pragma unroll
      for (int kw = 0; kw < 3; ++kw) {
        const int ww = w + kw - 1;
        float xv = (ww >= 0 && ww < Ww) ? xr[ww] : 0.f;
        float s = (xv > 0.f) ? 1.f : ((xv < 0.f) ? -1.f : 0.f);
        acc += s * wv[kh * 3 + kw];
      }
    }
  }
  if (w < Ww) out[obase] = acc * scale;
}

extern "C" void kernel_launch(void* const* d_in, const int* in_sizes, int n_in,
                              void* d_out, int out_size, void* d_ws, size_t ws_size,
                              hipStream_t stream) {
  const float* x    = (const float*)d_in[0];
  const float* wgt  = (const float*)d_in[1];
  const float* mask = (const float*)d_in[2];
  float* out = (float*)d_out;

  bool ok = ws_size >= WS_REQUIRED;
  if (ok) {
    hipError_t e = hipFuncSetAttribute(
        (const void*)gemm_i8w, hipFuncAttributeMaxDynamicSharedMemorySize,
        LDS_TOTAL);
    ok = (e == hipSuccess);
  }
  if (!ok) {
    hipLaunchKernelGGL(binconv_naive, dim3(Hh / 4, COUT, B_), dim3(64, 4, 1),
                       0, stream, x, wgt, mask, out);
    return;
  }

  signed char* xp8 = (signed char*)d_ws;
  signed char* awt = (signed char*)d_ws + AWT_OFF;
  int* meta        = (int*)((char*)d_ws + META_OFF);

  hipLaunchKernelGGL(prep_all, dim3(HP * B_ + 256), dim3(256), 0, stream,
                     x, wgt, mask, meta, awt, xp8);
  hipLaunchKernelGGL(gemm_i8w, dim3(448, 2), dim3(1024), LDS_TOTAL, stream,
                     xp8, awt, meta, out);
}

// Round 23
// 75.392 us; speedup vs baseline: 1.6607x; 1.0300x over previous
//
#include <hip/hip_runtime.h>

#define B_    32
#define CIN   256
#define COUT  256
#define Hh    56
#define Ww    56
#define HP    58
#define WP    58
#define Kk    2304   // 9 taps * 256 ci
#define NT    18     // K-tiles of BK=128 (2 per tap)

#define QSCALE 2016.0f
#define QINV   (1.0f/2016.0f)

#define XPAD_BYTES ((size_t)B_*HP*WP*CIN)     // 27,557,888 i8 (ci-slot swizzled)
#define XPAD_GUARD 16384                       // B-slab over-read guard
#define AWT_OFF    (XPAD_BYTES + XPAD_GUARD)
#define AWT_BYTES  ((size_t)NT*32768)          // weights tiled [kt][kc8][slot][16]
#define META_OFF   (AWT_OFF + AWT_BYTES)
#define WS_REQUIRED (META_OFF + 1040)

#define LDS_TOTAL 65536                        // B slab only: 4 rows + slack
#define TP 260                                 // prep tile row stride (bytes)

typedef __attribute__((ext_vector_type(4))) int i32x4;

__device__ __forceinline__ void gload_lds16(const void* g, void* l) {
  __builtin_amdgcn_global_load_lds(
      (const __attribute__((address_space(1))) unsigned int*)g,
      (__attribute__((address_space(3))) unsigned int*)l, 16, 0, 0);
}

// ---- fused prepass: blocks [0, HP*B_) sign+pad+transpose+SWIZZLE x;
// blocks [HP*B_, +256) mask-scan + gated-weight quant (slot-tiled, BK=128).
// xpad layout: [b][hp][wp][ci-swizzled]: byte at (wp, slot_p*16+b4) holds
// value of logical ci = (slot_p ^ (wp&15))*16 + b4  (involution).
// LDS tile rows padded to 260B (bank-conflict-free writes, r22 fix).
__global__ __launch_bounds__(256) void prep_all(
    const float* __restrict__ x,
    const float* __restrict__ wgt,
    const float* __restrict__ mask,
    int* __restrict__ meta,
    signed char* __restrict__ awt,
    signed char* __restrict__ xp) {
  const int t = threadIdx.x;
  const int bid = blockIdx.x;
  if (bid < HP * B_) {
    const int hp = bid % HP, b = bid / HP;
    unsigned* orow = (unsigned*)(xp + (size_t)(b * HP + hp) * WP * CIN);
    if (hp == 0 || hp == HP - 1) {
      for (int i = t; i < WP * CIN / 4; i += 256) orow[i] = 0u;
      return;
    }
    __shared__ __align__(16) signed char tile[WP * TP];
    const int h = hp - 1;
    tile[t] = 0;                               // wp=0 border (pad bytes unread)
    tile[(WP - 1) * TP + t] = 0;               // wp=57 border
    const int tx = t & 63, ty = t >> 6;
    if (tx < Ww) {
      const float* xr = x + ((size_t)b * CIN * Hh + h) * Ww;
      for (int ci0 = ty * 4; ci0 < CIN; ci0 += 16) {
        unsigned pk = 0;
        #pragma unroll
        for (int j = 0; j < 4; ++j) {
          float xv = xr[(size_t)(ci0 + j) * (Hh * Ww) + tx];
          unsigned s = (xv > 0.f) ? 1u : (xv < 0.f ? 0xFFu : 0u);
          pk |= s << (8 * j);
        }
        *(unsigned*)&tile[(1 + tx) * TP + ci0] = pk;
      }
    }
    __syncthreads();
    for (int i = t; i < WP * CIN / 4; i += 256) {
      const int byte = i * 4;
      const int wp = byte >> 8;
      const int slot_p = (byte >> 4) & 15;
      const int slot_l = slot_p ^ (wp & 15);
      orow[i] = *(const unsigned*)&tile[wp * TP + slot_l * 16 + (byte & 15)];
    }
  } else {
    __shared__ int sc[256];
    __shared__ int sperm[256];
    const int fl = (mask[t] >= 0.0f) ? 1 : 0;   // scale!=0 iff mask>=0
    sc[t] = fl;
    __syncthreads();
    for (int off = 1; off < 256; off <<= 1) {
      int v = sc[t];
      int u = (t >= off) ? sc[t - off] : 0;
      __syncthreads();
      sc[t] = v + u;
      __syncthreads();
    }
    const int incl = sc[t], act = sc[255];
    const int pos = fl ? (incl - 1) : (act + t - incl);
    sperm[pos] = t;
    __syncthreads();
    const int slot = bid - HP * B_;
    if (slot == 0) {
      meta[1 + pos] = t;
      if (t == 0) meta[0] = act;
    }
    const int co = sperm[slot];
    const float m = mask[co];
    const float scl = (m > 0.f ? 1.f : (m < 0.f ? 0.f : 0.5f)) * QSCALE;
    const float* wc = wgt + (size_t)co * Kk;     // [ci][tap]
    for (int o = t; o < Kk; o += 256) {
      int tap = o >> 8, ci = o & 255;
      int q = __float2int_rn(wc[ci * 9 + tap] * scl);
      int kt = tap * 2 + (ci >> 7);              // BK=128 K-tile
      int kk = ci & 127;
      awt[((size_t)kt * 2048 + (kk >> 4) * 256 + slot) * 16 + (kk & 15)] =
          (signed char)q;
    }
  }
}

// ---- main: compacted-M i8 GEMM, BARRIER-FREE K-loop.
// Block = 128 slots (by half) x 128 n (2 output rows x 64 w). 8 waves
// (4M x 2N) of 32x64, acc[2][4]=32 AGPR. B slab (4 hp rows, 64KB incl
// slack) resident in LDS, staged once (8 gload_lds/thread + ONE barrier).
// A-fragments load GLOBAL -> VGPR (L2-resident 294KB, fragment-ordered,
// coalesced), two-bank register prefetch, compiler-managed waits.
// K-loop has ZERO barriers / ZERO waitcnt asm: 16 waves/CU free-run.
// grid=(896 = b*28 + hblk, 2), block=512, 2 blocks/CU.
__global__ __launch_bounds__(512, 4) void gemm_i8f(
    const signed char* __restrict__ xp,
    const signed char* __restrict__ awt,
    const int* __restrict__ meta,
    float* __restrict__ out) {
  extern __shared__ char smem[];

  const int t = threadIdx.x;
  const int nb = blockIdx.x, by = blockIdx.y;
  const int b = nb / 28, h0 = (nb % 28) * 2;

  const int act = meta[0];
  const int rem = act - by * 128;
  const int g32 = (rem <= 0) ? 0 : ((rem >= 128) ? 4 : ((rem + 31) >> 5));

  const int wid = t >> 6, lane = t & 63;
  const int wm = wid >> 1, wn = wid & 1;     // 4M x 2N waves of 32x64
  const int lc = lane & 15, lr = lane >> 4;

  i32x4 acc[2][4] = {};

  if (g32 > 0) {
    // B slab: 8 linear loads/thread (64KB covers 4 rows = 59392B + slack)
    const signed char* xsrc = xp + ((size_t)b * HP + h0) * WP * CIN;
    char* dB = smem + t * 16;
    #pragma unroll
    for (int j = 0; j < 8; ++j)
      gload_lds16(xsrc + t * 16 + j * 8192, dB + j * 8192);
    asm volatile("s_waitcnt vmcnt(0)" ::: "memory");
    __builtin_amdgcn_sched_barrier(0);
    __builtin_amdgcn_s_barrier();
    __builtin_amdgcn_sched_barrier(0);

    // A global fragment base: + kt*32768 + kc*4096 + m*256
    const signed char* awg = awt + (size_t)(by * 128 + wm * 32 + lc) * 16;
    const bool run = (wm < g32);
    i32x4 afA[4], afB[4], bf[4];

#define LOAD_A_G(ktx, AF) do { if (run) { _Pragma("unroll")                    \
    for (int s_ = 0; s_ < 2; ++s_) { _Pragma("unroll")                         \
      for (int m_ = 0; m_ < 2; ++m_)                                           \
        AF[s_ * 2 + m_] = *(const i32x4*)(awg + (size_t)(ktx) * 32768 +        \
                                          (s_ * 4 + lr) * 4096 + m_ * 256); }  \
  } } while (0)

#define KT_COMP(ktx, AF) do { if (run) {                                       \
    const int tap_ = (ktx) >> 1;                                               \
    const int kh_ = tap_ / 3, kw_ = tap_ - kh_ * 3;                            \
    const int kbit_ = ((ktx) & 1) * 8;                                         \
    const int brow_ = ((wn + kh_) * WP) * 256;                                 \
    _Pragma("unroll")                                                          \
    for (int s_ = 0; s_ < 2; ++s_) {                                           \
      const int sl_ = kbit_ + s_ * 4 + lr;                                     \
      _Pragma("unroll")                                                        \
      for (int nf_ = 0; nf_ < 4; ++nf_) {                                      \
        const int wp_ = kw_ + nf_ * 16 + lc;                                   \
        bf[nf_] = *(const i32x4*)(smem + brow_ + wp_ * 256 +                   \
                                  ((sl_ ^ (wp_ & 15)) << 4));                  \
      }                                                                        \
      __builtin_amdgcn_s_setprio(1);                                           \
      _Pragma("unroll")                                                        \
      for (int m_ = 0; m_ < 2; ++m_) { _Pragma("unroll")                       \
        for (int n_ = 0; n_ < 4; ++n_)                                         \
          acc[m_][n_] = __builtin_amdgcn_mfma_i32_16x16x64_i8(                 \
              AF[s_ * 2 + m_], bf[n_], acc[m_][n_], 0, 0, 0); }                \
      __builtin_amdgcn_s_setprio(0);                                           \
    }                                                                          \
  } } while (0)

    LOAD_A_G(0, afA);
#pragma unroll 1
    for (int it = 0; it < NT / 2; ++it) {
      const int ka = 2 * it, kb = 2 * it + 1;
      const int kc2 = (kb + 1 < NT) ? kb + 1 : NT - 1;  // tail dummy ok
      LOAD_A_G(kb, afB);
      KT_COMP(ka, afA);
      LOAD_A_G(kc2, afA);
      KT_COMP(kb, afB);
    }
  }

  // epilogue: C/D map col(n)=lane&15, row(m)=(lane>>4)*4+reg.
  // wave covers h = h0 + wn, w = nf*16 + lc. slot -> co via perm.
  const int* perm = meta + 1;
  const int h = h0 + wn;
  #pragma unroll
  for (int m = 0; m < 2; ++m) {
    const int slotb = by * 128 + wm * 32 + m * 16 + lr * 4;
    const int c0 = perm[slotb], c1 = perm[slotb + 1];
    const int c2 = perm[slotb + 2], c3 = perm[slotb + 3];
    const int cos[4] = {c0, c1, c2, c3};
    #pragma unroll
    for (int nf = 0; nf < 4; ++nf) {
      const int w = nf * 16 + lc;
      if (w < Ww) {
        #pragma unroll
        for (int r = 0; r < 4; ++r)
          out[(((size_t)b * COUT + cos[r]) * Hh + h) * Ww + w] =
              (float)acc[m][nf][r] * QINV;
      }
    }
  }
}

// ---- fallback: proven-correct naive direct conv (used only if ws too small)
__global__ __launch_bounds__(256) void binconv_naive(
    const float* __restrict__ x,
    const float* __restrict__ wgt,
    const float* __restrict__ mask,
    float* __restrict__ out) {
  const int w  = threadIdx.x;
  const int h  = blockIdx.x * 4 + threadIdx.y;
  const int co = blockIdx.y;
  const int b  = blockIdx.z;

  const float m = mask[co];
  const float scale = (m > 0.f) ? 1.f : ((m < 0.f) ? 0.f : 0.5f);

  const size_t obase = (((size_t)b * COUT + co) * Hh + h) * Ww + w;
  if (scale == 0.f) {
    if (w < Ww) out[obase] = 0.f;
    return;
  }

  const float* __restrict__ xb = x   + (size_t)b  * CIN * Hh * Ww;
  const float* __restrict__ wc = wgt + (size_t)co * CIN * 9;

  float acc = 0.f;
  for (int ci = 0; ci < CIN; ++ci) {
    const float* __restrict__ xc = xb + (size_t)ci * (Hh * Ww);
    const float* __restrict__ wk = wc + ci * 9;
    float wv[9];
    #pragma unroll
    for (int t2 = 0; t2 < 9; ++t2) wv[t2] = wk[t2];
    #pragma unroll
    for (int kh = 0; kh < 3; ++kh) {
      const int hh = h + kh - 1;
      if (hh < 0 || hh >= Hh) continue;
      const float* __restrict__ xr = xc + hh * Ww;
      #pragma unroll
      for (int kw = 0; kw < 3; ++kw) {
        const int ww = w + kw - 1;
        float xv = (ww >= 0 && ww < Ww) ? xr[ww] : 0.f;
        float s = (xv > 0.f) ? 1.f : ((xv < 0.f) ? -1.f : 0.f);
        acc += s * wv[kh * 3 + kw];
      }
    }
  }
  if (w < Ww) out[obase] = acc * scale;
}

extern "C" void kernel_launch(void* const* d_in, const int* in_sizes, int n_in,
                              void* d_out, int out_size, void* d_ws, size_t ws_size,
                              hipStream_t stream) {
  const float* x    = (const float*)d_in[0];
  const float* wgt  = (const float*)d_in[1];
  const float* mask = (const float*)d_in[2];
  float* out = (float*)d_out;

  bool ok = ws_size >= WS_REQUIRED;
  if (ok) {
    hipError_t e = hipFuncSetAttribute(
        (const void*)gemm_i8f, hipFuncAttributeMaxDynamicSharedMemorySize,
        LDS_TOTAL);
    ok = (e == hipSuccess);
  }
  if (!ok) {
    hipLaunchKernelGGL(binconv_naive, dim3(Hh / 4, COUT, B_), dim3(64, 4, 1),
                       0, stream, x, wgt, mask, out);
    return;
  }

  signed char* xp8 = (signed char*)d_ws;
  signed char* awt = (signed char*)d_ws + AWT_OFF;
  int* meta        = (int*)((char*)d_ws + META_OFF);

  hipLaunchKernelGGL(prep_all, dim3(HP * B_ + 256), dim3(256), 0, stream,
                     x, wgt, mask, meta, awt, xp8);
  hipLaunchKernelGGL(gemm_i8f, dim3(896, 2), dim3(512), LDS_TOTAL, stream,
                     xp8, awt, meta, out);
}